// Round 6
// baseline (549.931 us; speedup 1.0000x reference)
//
#include <hip/hip_runtime.h>

// JointNet: out[n,t,u,v] = tanh(enc_proj[t,n,:] + pred_proj[u,n,:] + b1) . W2^T + b2
// T=200 U=50 N=8  ENC=PRED=512  H=640  V=1000
// m = ((n*200+t)*50+u) -> flat row-major [80000][1000] GEMM with A generated on the fly.
// Round-6: round-4 2-phase structure; B staged via global_load_lds (16B, pre-swizzled
// source, linear LDS dest); A reg-staged with tanh; 3 WG/CU.

typedef __attribute__((ext_vector_type(4))) float f32x4;
typedef __attribute__((ext_vector_type(8))) short s16x8;

#define HDIM 640
#define VOCAB 1000

__device__ __forceinline__ float tanh_fast(float x) {
  float e = __expf(2.0f * x);
  return 1.0f - 2.0f * __builtin_amdgcn_rcpf(e + 1.0f);
}

__device__ __forceinline__ unsigned short f2bf(float f) {
  unsigned int u = __float_as_uint(f);
  return (unsigned short)((u + 0x7FFFu + ((u >> 16) & 1u)) >> 16);  // RNE
}

__device__ __forceinline__ void gload_lds16(const void* g, void* l) {
  __builtin_amdgcn_global_load_lds((const __attribute__((address_space(1))) void*)g,
                                   (__attribute__((address_space(3))) void*)l, 16, 0, 0);
}

// ---- K0: W2 f32 [1000][640] -> bf16 [1024][640], rows 1000..1023 zero ----
__global__ void k_prep(const float* __restrict__ W2, unsigned short* __restrict__ W2b) {
  int i = blockIdx.x * 256 + threadIdx.x;  // 81920 = 1024*640/8
  int v = i / 80;
  int kc = (i - v * 80) * 8;
  s16x8 o = {0, 0, 0, 0, 0, 0, 0, 0};
  if (v < VOCAB) {
    const float* src = W2 + v * HDIM + kc;
    f32x4 a = *(const f32x4*)src;
    f32x4 b = *(const f32x4*)(src + 4);
#pragma unroll
    for (int j = 0; j < 4; ++j) {
      o[j] = (short)f2bf(a[j]);
      o[j + 4] = (short)f2bf(b[j]);
    }
  }
  *(s16x8*)(W2b + (size_t)v * HDIM + kc) = o;
}

// ---- K1: projections, f32 tiled GEMM ----
__global__ __launch_bounds__(256) void k_proj(const float* __restrict__ enc,
                                              const float* __restrict__ pred,
                                              const float* __restrict__ W1,
                                              const float* __restrict__ b1,
                                              float* __restrict__ EPPB) {
  __shared__ float As[16][68];
  __shared__ float Bs[16][68];
  const int tid = threadIdx.x;
  const int tx = tid & 15, ty = tid >> 4;
  const int h0 = blockIdx.x * 64;
  const int m0 = blockIdx.y * 64;
  const bool isPred = (m0 >= 1600);
  const float* A = isPred ? pred : enc;
  const int arow0 = isPred ? (m0 - 1600) : m0;
  const int armax = isPred ? 399 : 1599;
  const int koff = isPred ? 512 : 0;
  float acc[4][4] = {};
  for (int k0 = 0; k0 < 512; k0 += 16) {
#pragma unroll
    for (int q = 0; q < 4; ++q) {
      int r = ty + q * 16;
      int ar = arow0 + r;
      if (ar > armax) ar = armax;
      As[tx][r] = A[ar * 512 + k0 + tx];
      Bs[tx][r] = W1[(h0 + r) * 1024 + koff + k0 + tx];
    }
    __syncthreads();
#pragma unroll
    for (int kk = 0; kk < 16; ++kk) {
      f32x4 a = *(const f32x4*)&As[kk][ty * 4];
      f32x4 b = *(const f32x4*)&Bs[kk][tx * 4];
#pragma unroll
      for (int i = 0; i < 4; ++i)
#pragma unroll
        for (int j = 0; j < 4; ++j) acc[i][j] += a[i] * b[j];
    }
    __syncthreads();
  }
#pragma unroll
  for (int i = 0; i < 4; ++i) {
    int m = m0 + ty * 4 + i;
    if (m < 2000) {
#pragma unroll
      for (int j = 0; j < 4; ++j) {
        int h = h0 + tx * 4 + j;
        float val = acc[i][j];
        if (m >= 1600) val += b1[h];
        EPPB[m * HDIM + h] = val;
      }
    }
  }
}

// ---- K2: fused joint GEMM, 128m x 256v tile, BK=64, single-buffer 2-phase ----
__global__ __launch_bounds__(256, 3) void k_joint(const float* __restrict__ EPPB,
                                                  const unsigned short* __restrict__ W2b,
                                                  const float* __restrict__ b2,
                                                  float* __restrict__ out) {
  __shared__ char Asm[16384];  // A: 128 rows x 128 B, XOR-swizzled image
  __shared__ char Bsm[32768];  // B: 256 rows x 128 B, XOR-swizzled image

  // bijective XCD-chunked swizzle over 2500 WGs (2500 = 8*312 + 4)
  const int bid = blockIdx.x;
  const int xcd = bid & 7, seq = bid >> 3;
  const int swz = (xcd < 4 ? xcd * 313 : 1252 + (xcd - 4) * 312) + seq;
  const int mtile = swz >> 2;
  const int vtile = swz & 3;
  const int m0 = mtile * 128;
  const int v0 = vtile * 256;

  const int tid = threadIdx.x;

  // ---- A staging setup: 4 chunks/thread (1024 = 128 rows x 8 kchunks) ----
  int epoff[4], pboff[4], aoff[4];
#pragma unroll
  for (int s = 0; s < 4; ++s) {
    int c = s * 256 + tid;
    int row = c >> 3, kc = c & 7;
    int m = m0 + row;
    int n = m / 10000;
    int rr = m - n * 10000;
    int t = rr / 50;
    int u = rr - t * 50;
    epoff[s] = (t * 8 + n) * HDIM + kc * 8;
    pboff[s] = (1600 + u * 8 + n) * HDIM + kc * 8;
    aoff[s] = row * 128 + ((kc * 16) ^ ((row & 7) << 4));
  }

  // ---- B staging setup: 8 gload_lds chunks/thread (2048 = 256 rows x 8 kchunks)
  // global source pre-swizzled; LDS dest linear (wave-uniform base + lane*16).
  const char* const w2bytes = (const char*)W2b;
  int bgoff[8];
#pragma unroll
  for (int s = 0; s < 8; ++s) {
    int c = s * 256 + tid;
    int row = c >> 3, kc = c & 7;
    bgoff[s] = (v0 + row) * 1280 + ((kc * 16) ^ ((row & 7) << 4));
  }
  const int bldsbase = (tid >> 6) * 1024;  // + s*4096 per chunk group

  const int wid = tid >> 6;
  const int lane = tid & 63;
  const int mrow = (wid >> 1) * 64;   // 2 m-waves x 2 v-waves
  const int vrow = (wid & 1) * 128;
  const int lr = lane & 15;
  const int kq = lane >> 4;
  const int sw = (lr & 7) << 4;

  f32x4 acc[4][8];
  const f32x4 zero = {0.0f, 0.0f, 0.0f, 0.0f};
#pragma unroll
  for (int mi = 0; mi < 4; ++mi)
#pragma unroll
    for (int ni = 0; ni < 8; ++ni) acc[mi][ni] = zero;

#pragma unroll 1
  for (int ks = 0; ks < 10; ++ks) {
    // phase 1a: A global -> regs (overlaps previous step's MFMAs), tanh+pack
    s16x8 aq[4];
#pragma unroll
    for (int s = 0; s < 4; ++s) {
      const float* ep = EPPB + epoff[s] + ks * 64;
      const float* pb = EPPB + pboff[s] + ks * 64;
      f32x4 e0 = *(const f32x4*)ep;
      f32x4 e1 = *(const f32x4*)(ep + 4);
      f32x4 p0 = *(const f32x4*)pb;
      f32x4 p1 = *(const f32x4*)(pb + 4);
#pragma unroll
      for (int i = 0; i < 4; ++i) {
        aq[s][i] = (short)f2bf(tanh_fast(e0[i] + p0[i]));
        aq[s][i + 4] = (short)f2bf(tanh_fast(e1[i] + p1[i]));
      }
    }
    __syncthreads();  // prior MFMA phase done reading LDS

    // phase 1b: B global -> LDS direct (async, drained by next barrier)
#pragma unroll
    for (int s = 0; s < 8; ++s)
      gload_lds16(w2bytes + bgoff[s] + ks * 128, Bsm + s * 4096 + bldsbase);
    // A regs -> LDS
#pragma unroll
    for (int s = 0; s < 4; ++s) *(s16x8*)(Asm + aoff[s]) = aq[s];
    __syncthreads();  // staged data visible (vmcnt+lgkm drained)

    // phase 2: MFMA
#pragma unroll
    for (int kk = 0; kk < 2; ++kk) {
      const int kt = (kk * 64 + kq * 16) ^ sw;
      s16x8 afr[4], bfr[8];
#pragma unroll
      for (int mi = 0; mi < 4; ++mi)
        afr[mi] = *(const s16x8*)(Asm + (mrow + mi * 16 + lr) * 128 + kt);
#pragma unroll
      for (int ni = 0; ni < 8; ++ni)
        bfr[ni] = *(const s16x8*)(Bsm + (vrow + ni * 16 + lr) * 128 + kt);
      __builtin_amdgcn_s_setprio(1);
#pragma unroll
      for (int mi = 0; mi < 4; ++mi)
#pragma unroll
        for (int ni = 0; ni < 8; ++ni)
          // swapped operands: D row = v (4 consecutive per lane), col = m
          acc[mi][ni] = __builtin_amdgcn_mfma_f32_16x16x32_bf16(bfr[ni], afr[mi], acc[mi][ni], 0, 0, 0);
      __builtin_amdgcn_s_setprio(0);
    }
  }

  // epilogue: lane holds 4 consecutive v per acc reg -> float4 stores
#pragma unroll
  for (int ni = 0; ni < 8; ++ni) {
    int vq = v0 + vrow + ni * 16 + kq * 4;
    if (vq < VOCAB) {
      f32x4 bv = *(const f32x4*)(b2 + vq);
#pragma unroll
      for (int mi = 0; mi < 4; ++mi) {
        int m = m0 + mrow + mi * 16 + lr;
        f32x4 r = acc[mi][ni] + bv;
        *(f32x4*)(out + (size_t)m * VOCAB + vq) = r;
      }
    }
  }
}

extern "C" void kernel_launch(void* const* d_in, const int* in_sizes, int n_in,
                              void* d_out, int out_size, void* d_ws, size_t ws_size,
                              hipStream_t stream) {
  const float* enc = (const float*)d_in[0];
  const float* pred = (const float*)d_in[1];
  const float* W1 = (const float*)d_in[2];
  const float* b1 = (const float*)d_in[3];
  const float* W2 = (const float*)d_in[4];
  const float* b2 = (const float*)d_in[5];
  float* out = (float*)d_out;

  unsigned short* W2b = (unsigned short*)d_ws;    // 1,310,720 B
  float* EPPB = (float*)((char*)d_ws + 1310720);  // 5,120,000 B

  k_prep<<<320, 256, 0, stream>>>(W2, W2b);
  k_proj<<<dim3(10, 32), 256, 0, stream>>>(enc, pred, W1, b1, EPPB);
  k_joint<<<2500, 256, 0, stream>>>(EPPB, W2b, b2, out);
}

// Round 7
// 232.609 us; speedup vs baseline: 2.3642x; 2.3642x over previous
//
#include <hip/hip_runtime.h>

// JointNet: out[n,t,u,v] = tanh(enc_proj[t,n,:] + pred_proj[u,n,:] + b1) . W2^T + b2
// T=200 U=50 N=8  ENC=PRED=512  H=640  V=1000
// m = ((n*200+t)*50+u) -> flat row-major [80000][1000] GEMM with A generated on the fly.
// Round-7: round-6 structure (B via global_load_lds, pre-swizzled source, linear LDS
// dest) with the proven (256,2) register budget — acc[4][8] needs >84 VGPRs; (256,3)
// spills (R3/R6 evidence: WRITE_SIZE 2-5x ideal).

typedef __attribute__((ext_vector_type(4))) float f32x4;
typedef __attribute__((ext_vector_type(8))) short s16x8;

#define HDIM 640
#define VOCAB 1000

__device__ __forceinline__ float tanh_fast(float x) {
  float e = __expf(2.0f * x);
  return 1.0f - 2.0f * __builtin_amdgcn_rcpf(e + 1.0f);
}

__device__ __forceinline__ unsigned short f2bf(float f) {
  unsigned int u = __float_as_uint(f);
  return (unsigned short)((u + 0x7FFFu + ((u >> 16) & 1u)) >> 16);  // RNE
}

__device__ __forceinline__ void gload_lds16(const void* g, void* l) {
  __builtin_amdgcn_global_load_lds((const __attribute__((address_space(1))) void*)g,
                                   (__attribute__((address_space(3))) void*)l, 16, 0, 0);
}

// ---- K0: W2 f32 [1000][640] -> bf16 [1024][640], rows 1000..1023 zero ----
__global__ void k_prep(const float* __restrict__ W2, unsigned short* __restrict__ W2b) {
  int i = blockIdx.x * 256 + threadIdx.x;  // 81920 = 1024*640/8
  int v = i / 80;
  int kc = (i - v * 80) * 8;
  s16x8 o = {0, 0, 0, 0, 0, 0, 0, 0};
  if (v < VOCAB) {
    const float* src = W2 + v * HDIM + kc;
    f32x4 a = *(const f32x4*)src;
    f32x4 b = *(const f32x4*)(src + 4);
#pragma unroll
    for (int j = 0; j < 4; ++j) {
      o[j] = (short)f2bf(a[j]);
      o[j + 4] = (short)f2bf(b[j]);
    }
  }
  *(s16x8*)(W2b + (size_t)v * HDIM + kc) = o;
}

// ---- K1: projections, f32 tiled GEMM ----
__global__ __launch_bounds__(256) void k_proj(const float* __restrict__ enc,
                                              const float* __restrict__ pred,
                                              const float* __restrict__ W1,
                                              const float* __restrict__ b1,
                                              float* __restrict__ EPPB) {
  __shared__ float As[16][68];
  __shared__ float Bs[16][68];
  const int tid = threadIdx.x;
  const int tx = tid & 15, ty = tid >> 4;
  const int h0 = blockIdx.x * 64;
  const int m0 = blockIdx.y * 64;
  const bool isPred = (m0 >= 1600);
  const float* A = isPred ? pred : enc;
  const int arow0 = isPred ? (m0 - 1600) : m0;
  const int armax = isPred ? 399 : 1599;
  const int koff = isPred ? 512 : 0;
  float acc[4][4] = {};
  for (int k0 = 0; k0 < 512; k0 += 16) {
#pragma unroll
    for (int q = 0; q < 4; ++q) {
      int r = ty + q * 16;
      int ar = arow0 + r;
      if (ar > armax) ar = armax;
      As[tx][r] = A[ar * 512 + k0 + tx];
      Bs[tx][r] = W1[(h0 + r) * 1024 + koff + k0 + tx];
    }
    __syncthreads();
#pragma unroll
    for (int kk = 0; kk < 16; ++kk) {
      f32x4 a = *(const f32x4*)&As[kk][ty * 4];
      f32x4 b = *(const f32x4*)&Bs[kk][tx * 4];
#pragma unroll
      for (int i = 0; i < 4; ++i)
#pragma unroll
        for (int j = 0; j < 4; ++j) acc[i][j] += a[i] * b[j];
    }
    __syncthreads();
  }
#pragma unroll
  for (int i = 0; i < 4; ++i) {
    int m = m0 + ty * 4 + i;
    if (m < 2000) {
#pragma unroll
      for (int j = 0; j < 4; ++j) {
        int h = h0 + tx * 4 + j;
        float val = acc[i][j];
        if (m >= 1600) val += b1[h];
        EPPB[m * HDIM + h] = val;
      }
    }
  }
}

// ---- K2: fused joint GEMM, 128m x 256v tile, BK=64, single-buffer 2-phase ----
__global__ __launch_bounds__(256, 2) void k_joint(const float* __restrict__ EPPB,
                                                  const unsigned short* __restrict__ W2b,
                                                  const float* __restrict__ b2,
                                                  float* __restrict__ out) {
  __shared__ char Asm[16384];  // A: 128 rows x 128 B, XOR-swizzled image
  __shared__ char Bsm[32768];  // B: 256 rows x 128 B, XOR-swizzled image

  // bijective XCD-chunked swizzle over 2500 WGs (2500 = 8*312 + 4)
  const int bid = blockIdx.x;
  const int xcd = bid & 7, seq = bid >> 3;
  const int swz = (xcd < 4 ? xcd * 313 : 1252 + (xcd - 4) * 312) + seq;
  const int mtile = swz >> 2;
  const int vtile = swz & 3;
  const int m0 = mtile * 128;
  const int v0 = vtile * 256;

  const int tid = threadIdx.x;

  // ---- A staging setup: 4 chunks/thread (1024 = 128 rows x 8 kchunks) ----
  int epoff[4], pboff[4], aoff[4];
#pragma unroll
  for (int s = 0; s < 4; ++s) {
    int c = s * 256 + tid;
    int row = c >> 3, kc = c & 7;
    int m = m0 + row;
    int n = m / 10000;
    int rr = m - n * 10000;
    int t = rr / 50;
    int u = rr - t * 50;
    epoff[s] = (t * 8 + n) * HDIM + kc * 8;
    pboff[s] = (1600 + u * 8 + n) * HDIM + kc * 8;
    aoff[s] = row * 128 + ((kc * 16) ^ ((row & 7) << 4));
  }

  // ---- B staging setup: 8 gload_lds chunks/thread (2048 = 256 rows x 8 kchunks)
  // global source pre-swizzled; LDS dest linear (wave-uniform base + lane*16).
  const char* const w2bytes = (const char*)W2b;
  int bgoff[8];
#pragma unroll
  for (int s = 0; s < 8; ++s) {
    int c = s * 256 + tid;
    int row = c >> 3, kc = c & 7;
    bgoff[s] = (v0 + row) * 1280 + ((kc * 16) ^ ((row & 7) << 4));
  }
  const int bldsbase = (tid >> 6) * 1024;  // + s*4096 per chunk group

  const int wid = tid >> 6;
  const int lane = tid & 63;
  const int mrow = (wid >> 1) * 64;   // 2 m-waves x 2 v-waves
  const int vrow = (wid & 1) * 128;
  const int lr = lane & 15;
  const int kq = lane >> 4;
  const int sw = (lr & 7) << 4;

  f32x4 acc[4][8];
  const f32x4 zero = {0.0f, 0.0f, 0.0f, 0.0f};
#pragma unroll
  for (int mi = 0; mi < 4; ++mi)
#pragma unroll
    for (int ni = 0; ni < 8; ++ni) acc[mi][ni] = zero;

#pragma unroll 1
  for (int ks = 0; ks < 10; ++ks) {
    // phase 1a: A global -> regs (overlaps previous step's MFMAs), tanh+pack
    s16x8 aq[4];
#pragma unroll
    for (int s = 0; s < 4; ++s) {
      const float* ep = EPPB + epoff[s] + ks * 64;
      const float* pb = EPPB + pboff[s] + ks * 64;
      f32x4 e0 = *(const f32x4*)ep;
      f32x4 e1 = *(const f32x4*)(ep + 4);
      f32x4 p0 = *(const f32x4*)pb;
      f32x4 p1 = *(const f32x4*)(pb + 4);
#pragma unroll
      for (int i = 0; i < 4; ++i) {
        aq[s][i] = (short)f2bf(tanh_fast(e0[i] + p0[i]));
        aq[s][i + 4] = (short)f2bf(tanh_fast(e1[i] + p1[i]));
      }
    }
    __syncthreads();  // prior MFMA phase done reading LDS

    // phase 1b: B global -> LDS direct (async, drained by next barrier)
#pragma unroll
    for (int s = 0; s < 8; ++s)
      gload_lds16(w2bytes + bgoff[s] + ks * 128, Bsm + s * 4096 + bldsbase);
    // A regs -> LDS
#pragma unroll
    for (int s = 0; s < 4; ++s) *(s16x8*)(Asm + aoff[s]) = aq[s];
    __syncthreads();  // staged data visible (vmcnt+lgkm drained)

    // phase 2: MFMA
#pragma unroll
    for (int kk = 0; kk < 2; ++kk) {
      const int kt = (kk * 64 + kq * 16) ^ sw;
      s16x8 afr[4], bfr[8];
#pragma unroll
      for (int mi = 0; mi < 4; ++mi)
        afr[mi] = *(const s16x8*)(Asm + (mrow + mi * 16 + lr) * 128 + kt);
#pragma unroll
      for (int ni = 0; ni < 8; ++ni)
        bfr[ni] = *(const s16x8*)(Bsm + (vrow + ni * 16 + lr) * 128 + kt);
      __builtin_amdgcn_s_setprio(1);
#pragma unroll
      for (int mi = 0; mi < 4; ++mi)
#pragma unroll
        for (int ni = 0; ni < 8; ++ni)
          // swapped operands: D row = v (4 consecutive per lane), col = m
          acc[mi][ni] = __builtin_amdgcn_mfma_f32_16x16x32_bf16(bfr[ni], afr[mi], acc[mi][ni], 0, 0, 0);
      __builtin_amdgcn_s_setprio(0);
    }
  }

  // epilogue: lane holds 4 consecutive v per acc reg -> float4 stores
#pragma unroll
  for (int ni = 0; ni < 8; ++ni) {
    int vq = v0 + vrow + ni * 16 + kq * 4;
    if (vq < VOCAB) {
      f32x4 bv = *(const f32x4*)(b2 + vq);
#pragma unroll
      for (int mi = 0; mi < 4; ++mi) {
        int m = m0 + mrow + mi * 16 + lr;
        f32x4 r = acc[mi][ni] + bv;
        *(f32x4*)(out + (size_t)m * VOCAB + vq) = r;
      }
    }
  }
}

extern "C" void kernel_launch(void* const* d_in, const int* in_sizes, int n_in,
                              void* d_out, int out_size, void* d_ws, size_t ws_size,
                              hipStream_t stream) {
  const float* enc = (const float*)d_in[0];
  const float* pred = (const float*)d_in[1];
  const float* W1 = (const float*)d_in[2];
  const float* b1 = (const float*)d_in[3];
  const float* W2 = (const float*)d_in[4];
  const float* b2 = (const float*)d_in[5];
  float* out = (float*)d_out;

  unsigned short* W2b = (unsigned short*)d_ws;    // 1,310,720 B
  float* EPPB = (float*)((char*)d_ws + 1310720);  // 5,120,000 B

  k_prep<<<320, 256, 0, stream>>>(W2, W2b);
  k_proj<<<dim3(10, 32), 256, 0, stream>>>(enc, pred, W1, b1, EPPB);
  k_joint<<<2500, 256, 0, stream>>>(EPPB, W2b, b2, out);
}